// Round 2
// baseline (34294.626 us; speedup 1.0000x reference)
//
#include <hip/hip_runtime.h>
#include <hip/hip_bf16.h>
#include <type_traits>

#define S_LEN 1024
#define BATCH 16
#define HID   384
#define DIN   768

// ---------------- LSTM scan configuration ----------------
#define NBLK 48                // blocks per direction (96 total, all resident)
#define UBLK 8                 // hidden units per block (48*8 = 384)
#define HSTR 388               // LDS row stride for h (bank-pad: 388%32==4 dwords)

__device__ __forceinline__ float sigf(float x)     { return 1.f/(1.f + __expf(-x)); }
__device__ __forceinline__ float tanhfast(float x) { return 1.f - 2.f/(__expf(2.f*x) + 1.f); }

// ---------------- zero init for h-exchange buffers + barrier counters ----------------
__global__ void zero_kernel(float* hbuf, unsigned int* cnt)
{
    int i = blockIdx.x * blockDim.x + threadIdx.x;
    if (i < 2*2*BATCH*HID) hbuf[i] = 0.f;   // 24576 floats
    if (i < 64) cnt[i] = 0u;
}

// ---------------- generic fp32 GEMM: C = act(A @ W^T + bias), OT output ----------------
// A [M,K] ldA, W [N,K], C [M,N] ldC.  BM=128 BN=64 BK=16, 256 threads.
template<int RELU, typename OT>
__global__ __launch_bounds__(256) void gemm_nt(
    const float* __restrict__ A, int ldA,
    const float* __restrict__ W,
    const float* __restrict__ bias,
    OT* __restrict__ C, int ldC,
    int M, int N, int K)
{
    __shared__ float As[16][132];
    __shared__ float Ws[16][68];
    const int tid = threadIdx.x;
    const int m0 = blockIdx.x * 128;
    const int n0 = blockIdx.y * 64;
    const int tm = (tid & 15) * 8;
    const int tn = (tid >> 4) * 4;

    float acc[8][4];
    #pragma unroll
    for (int i = 0; i < 8; i++)
        #pragma unroll
        for (int j = 0; j < 4; j++) acc[i][j] = 0.f;

    const int lrow = tid >> 2;          // 0..63
    const int lk   = (tid & 3) * 4;     // 0,4,8,12

    for (int k0 = 0; k0 < K; k0 += 16) {
        #pragma unroll
        for (int p = 0; p < 2; p++) {
            const int r = lrow + p * 64;
            const float4 av = *(const float4*)(A + (size_t)(m0 + r) * ldA + k0 + lk);
            As[lk+0][r] = av.x; As[lk+1][r] = av.y; As[lk+2][r] = av.z; As[lk+3][r] = av.w;
        }
        {
            float4 wv = make_float4(0.f, 0.f, 0.f, 0.f);
            if (n0 + lrow < N) wv = *(const float4*)(W + (size_t)(n0 + lrow) * K + k0 + lk);
            Ws[lk+0][lrow] = wv.x; Ws[lk+1][lrow] = wv.y; Ws[lk+2][lrow] = wv.z; Ws[lk+3][lrow] = wv.w;
        }
        __syncthreads();
        #pragma unroll
        for (int k = 0; k < 16; k++) {
            const float4 a0 = *(const float4*)&As[k][tm];
            const float4 a1 = *(const float4*)&As[k][tm + 4];
            const float4 bv = *(const float4*)&Ws[k][tn];
            const float am[8] = {a0.x, a0.y, a0.z, a0.w, a1.x, a1.y, a1.z, a1.w};
            const float bb[4] = {bv.x, bv.y, bv.z, bv.w};
            #pragma unroll
            for (int i = 0; i < 8; i++)
                #pragma unroll
                for (int j = 0; j < 4; j++) acc[i][j] += am[i] * bb[j];
        }
        __syncthreads();
    }

    #pragma unroll
    for (int i = 0; i < 8; i++) {
        const int m = m0 + tm + i;
        #pragma unroll
        for (int j = 0; j < 4; j++) {
            const int n = n0 + tn + j;
            if (n < N) {
                float v = acc[i][j] + bias[n];
                if (RELU) v = fmaxf(v, 0.f);
                if constexpr (std::is_same_v<OT, __hip_bfloat16>)
                    C[(size_t)m * ldC + n] = __float2bfloat16(v);
                else
                    C[(size_t)m * ldC + n] = v;
            }
        }
    }
}

// ---------------- persistent LSTM scan (one layer, both directions) ----------------
// grid = 96 blocks (48 fwd + 48 bwd), 512 threads, 25 KB static LDS.
// gates* = bf16 precomputed x@Wih^T + b, layout [16][1024][1536] (i,f,g,o).
// out [16][1024][768]; fwd -> cols 0..383, bwd -> 384..767.
// h exchange via agent-scope atomics in hbuf (coherent at Infinity Cache across XCDs).
__global__ __launch_bounds__(512) void lstm_scan(
    const __hip_bfloat16* __restrict__ gatesF, const __hip_bfloat16* __restrict__ gatesB,
    const float* __restrict__ WhhF,            const float* __restrict__ WhhB,
    float* __restrict__ out, float* hbuf, unsigned int* cnt)
{
    __shared__ float hl[BATCH * HSTR];         // staged h_prev, fp32

    const int blk = blockIdx.x;
    const int dir = blk / NBLK;
    const int u0  = (blk % NBLK) * UBLK;
    const __hip_bfloat16* gates = dir ? gatesB : gatesF;
    const float* Whh = dir ? WhhB : WhhF;
    float* hbG = hbuf + dir * (2 * BATCH * HID);     // [2 slots][16][384]
    unsigned int* bar = cnt + dir * 32;              // separate 128B lines

    const int tid = threadIdx.x;
    const int kp  = tid & 3;            // k-part, lane bits 0..1 (strided k: kp*4 + m*16)
    const int b   = (tid >> 2) & 15;    // batch
    const int u   = tid >> 6;           // 0..7 local unit
    const int u_glob = u0 + u;
    const bool owner = (kp == 0);

    // per-thread weight row pointers (4 gates)
    const float* wp0 = Whh + (size_t)(0*HID + u_glob) * HID;
    const float* wp1 = Whh + (size_t)(1*HID + u_glob) * HID;
    const float* wp2 = Whh + (size_t)(2*HID + u_glob) * HID;
    const float* wp3 = Whh + (size_t)(3*HID + u_glob) * HID;

    // precompute h-staging LDS destinations (t-invariant): 3072 u64 = 512 thr x 6
    int dst_off[6];
    #pragma unroll
    for (int j = 0; j < 6; j++) {
        const int f = 2 * (tid + 512 * j);      // flat float index 0..6142
        const int bb = f / 384;
        dst_off[j] = bb * HSTR + (f - bb * 384);
    }
    const int hrow = b * HSTR;

    float c_state = 0.f;

    for (int t = 0; t < S_LEN; t++) {
        const int tt = dir ? (S_LEN - 1 - t) : t;

        // prefetch this step's gate pre-activations (owners only) — hides HBM latency
        float gxi = 0.f, gxf = 0.f, gxg = 0.f, gxo = 0.f;
        if (owner) {
            const __hip_bfloat16* gp = gates + ((size_t)(b * S_LEN + tt)) * (4 * HID) + u_glob;
            gxi = __bfloat162float(gp[0]);
            gxf = __bfloat162float(gp[HID]);
            gxg = __bfloat162float(gp[2 * HID]);
            gxo = __bfloat162float(gp[3 * HID]);
        }

        // stage h_prev from IC-coherent buffer into LDS (8B agent-scope atomic loads)
        {
            const unsigned long long* src =
                (const unsigned long long*)(hbG + (t & 1) * (BATCH * HID));
            #pragma unroll
            for (int j = 0; j < 6; j++) {
                unsigned long long q = __hip_atomic_load(src + tid + 512 * j,
                                        __ATOMIC_RELAXED, __HIP_MEMORY_SCOPE_AGENT);
                union { unsigned long long q; float2 f; } cv; cv.q = q;
                *(float2*)(hl + dst_off[j]) = cv.f;
            }
        }
        __syncthreads();

        // partial dot: 4 gates, k-slice {kp*4 + m*16}, 24 float4 chunks
        float a0 = 0.f, a1 = 0.f, a2 = 0.f, a3 = 0.f;
        #pragma unroll 4
        for (int m = 0; m < 24; m++) {
            const int k = kp * 4 + m * 16;
            const float4 h4 = *(const float4*)(hl + hrow + k);
            const float4 w0 = *(const float4*)(wp0 + k);
            const float4 w1 = *(const float4*)(wp1 + k);
            const float4 w2 = *(const float4*)(wp2 + k);
            const float4 w3 = *(const float4*)(wp3 + k);
            a0 += h4.x*w0.x + h4.y*w0.y + h4.z*w0.z + h4.w*w0.w;
            a1 += h4.x*w1.x + h4.y*w1.y + h4.z*w1.z + h4.w*w1.w;
            a2 += h4.x*w2.x + h4.y*w2.y + h4.z*w2.z + h4.w*w2.w;
            a3 += h4.x*w3.x + h4.y*w3.y + h4.z*w3.z + h4.w*w3.w;
        }
        // reduce over the 4 k-parts (lane bits 0..1)
        a0 += __shfl_xor(a0, 1, 64); a0 += __shfl_xor(a0, 2, 64);
        a1 += __shfl_xor(a1, 1, 64); a1 += __shfl_xor(a1, 2, 64);
        a2 += __shfl_xor(a2, 1, 64); a2 += __shfl_xor(a2, 2, 64);
        a3 += __shfl_xor(a3, 1, 64); a3 += __shfl_xor(a3, 2, 64);

        if (owner) {
            const float xi = a0 + gxi, xf = a1 + gxf, xg = a2 + gxg, xo = a3 + gxo;
            const float ii = sigf(xi), ff = sigf(xf), gg = tanhfast(xg), oo = sigf(xo);
            c_state = ff * c_state + ii * gg;
            const float hn = oo * tanhfast(c_state);
            // coherent (IC) store for next-step exchange
            __hip_atomic_store(hbG + ((t + 1) & 1) * (BATCH * HID) + b * HID + u_glob,
                               hn, __ATOMIC_RELAXED, __HIP_MEMORY_SCOPE_AGENT);
            // plain store for downstream kernels (kernel-boundary release covers it)
            out[((size_t)(b * S_LEN + tt)) * (2 * HID) + dir * HID + u_glob] = hn;
        }

        __syncthreads();   // all waves' stores drained (vmcnt(0) before s_barrier)
        if (tid == 0) {
            __builtin_amdgcn_fence(__ATOMIC_RELEASE, "agent");
            __hip_atomic_fetch_add(bar, 1u, __ATOMIC_RELAXED, __HIP_MEMORY_SCOPE_AGENT);
            const unsigned int target = (unsigned int)(NBLK * (t + 1));
            long guard = 0;
            while (__hip_atomic_load(bar, __ATOMIC_RELAXED, __HIP_MEMORY_SCOPE_AGENT) < target
                   && guard < 200000000L) { __builtin_amdgcn_s_sleep(1); ++guard; }
            __builtin_amdgcn_fence(__ATOMIC_ACQUIRE, "agent");
        }
        __syncthreads();
    }
}

// ---------------- windowed attention ----------------
// score_j = (h_i*w3 + w2) . h_j   (s1[i] and attn_b are constant over j -> cancel in softmax)
__global__ __launch_bounds__(256) void attn_win(
    const float* __restrict__ hcat,   // [16][1024][768], h in cols 0..383
    const float* __restrict__ attnW,  // [1152] = w1|w2|w3
    float* __restrict__ ocat,         // same buffer, writes cols 384..767
    const int* __restrict__ wsz_p)
{
    __shared__ float q[HID];
    __shared__ float sc[96];
    __shared__ float p[96];
    const int blk = blockIdx.x;
    const int b = blk >> 10, i = blk & 1023;
    const int W = *wsz_p;
    const int jlo = max(i - W, 0), jhi = min(i + W, S_LEN - 1);
    const int nj = jhi - jlo + 1;
    const int tid = threadIdx.x;
    const float* hrow = hcat + (size_t)b * S_LEN * 768;

    if (tid < 96) {
        const float4 hv = *(const float4*)(hrow + (size_t)i * 768 + tid * 4);
        const float4 w3 = *(const float4*)(attnW + 768 + tid * 4);
        const float4 w2 = *(const float4*)(attnW + 384 + tid * 4);
        float4 r;
        r.x = hv.x*w3.x + w2.x; r.y = hv.y*w3.y + w2.y;
        r.z = hv.z*w3.z + w2.z; r.w = hv.w*w3.w + w2.w;
        *(float4*)(q + tid * 4) = r;
    }
    __syncthreads();

    const int wv = tid >> 6, lane = tid & 63;
    for (int jj = wv; jj < nj; jj += 4) {
        const float* hj = hrow + (size_t)(jlo + jj) * 768;
        float s = 0.f;
        #pragma unroll
        for (int c = 0; c < 6; c++) { const int d = lane + 64*c; s += q[d] * hj[d]; }
        #pragma unroll
        for (int st = 1; st < 64; st <<= 1) s += __shfl_xor(s, st, 64);
        if (lane == 0) sc[jj] = s;
    }
    __syncthreads();

    if (tid < 64) {
        float v1 = (tid < nj) ? sc[tid] : -3e38f;
        float v2 = (64 + tid < nj) ? sc[64 + tid] : -3e38f;
        float m = fmaxf(v1, v2);
        #pragma unroll
        for (int st = 1; st < 64; st <<= 1) m = fmaxf(m, __shfl_xor(m, st, 64));
        float e1 = (tid < nj) ? __expf(v1 - m) : 0.f;
        float e2 = (64 + tid < nj) ? __expf(v2 - m) : 0.f;
        float sum = e1 + e2;
        #pragma unroll
        for (int st = 1; st < 64; st <<= 1) sum += __shfl_xor(sum, st, 64);
        const float inv = 1.f / sum;
        if (tid < nj) p[tid] = e1 * inv;
        if (64 + tid < nj) p[64 + tid] = e2 * inv;
    }
    __syncthreads();

    if (tid < 192) {
        const int d = tid * 2;
        float s0 = 0.f, s1 = 0.f;
        for (int jj = 0; jj < nj; jj++) {
            const float* hj = hrow + (size_t)(jlo + jj) * 768 + d;
            const float pj = p[jj];
            s0 += pj * hj[0]; s1 += pj * hj[1];
        }
        float* o = ocat + (size_t)b * S_LEN * 768 + (size_t)i * 768 + 384 + d;
        o[0] = s0; o[1] = s1;
    }
}

// ---------------- final 96 -> 1 dot ----------------
__global__ __launch_bounds__(256) void final_dot(
    const float* __restrict__ y2, const float* __restrict__ W3,
    const float* __restrict__ b3, float* __restrict__ outp)
{
    __shared__ float w[96];
    const int tid = threadIdx.x;
    if (tid < 96) w[tid] = W3[tid];
    __syncthreads();
    const int r = blockIdx.x * 256 + tid;
    const float* row = y2 + (size_t)r * 96;
    float s = 0.f;
    #pragma unroll
    for (int c = 0; c < 24; c++) {
        const float4 v = ((const float4*)row)[c];
        s += v.x*w[c*4] + v.y*w[c*4+1] + v.z*w[c*4+2] + v.w*w[c*4+3];
    }
    outp[r] = s + b3[0];
}

// ---------------- launcher ----------------
extern "C" void kernel_launch(void* const* d_in, const int* in_sizes, int n_in,
                              void* d_out, int out_size, void* d_ws, size_t ws_size,
                              hipStream_t stream)
{
    const float* x        = (const float*)d_in[0];
    const float* l1_Wih_f = (const float*)d_in[1];
    const float* l1_Whh_f = (const float*)d_in[2];
    const float* l1_b_f   = (const float*)d_in[3];
    const float* l1_Wih_b = (const float*)d_in[4];
    const float* l1_Whh_b = (const float*)d_in[5];
    const float* l1_b_b   = (const float*)d_in[6];
    const float* l2_Wih_f = (const float*)d_in[7];
    const float* l2_Whh_f = (const float*)d_in[8];
    const float* l2_b_f   = (const float*)d_in[9];
    const float* l2_Wih_b = (const float*)d_in[10];
    const float* l2_Whh_b = (const float*)d_in[11];
    const float* l2_b_b   = (const float*)d_in[12];
    const float* fc1_W    = (const float*)d_in[13];
    const float* fc1_b    = (const float*)d_in[14];
    const float* attn_W   = (const float*)d_in[15];
    /* d_in[16] attn_b: cancels in softmax */
    const float* w1       = (const float*)d_in[17];
    const float* b1       = (const float*)d_in[18];
    const float* w2       = (const float*)d_in[19];
    const float* b2       = (const float*)d_in[20];
    const float* w3       = (const float*)d_in[21];
    const float* b3       = (const float*)d_in[22];
    const int*   wsz      = (const int*)d_in[23];

    // workspace layout (bytes), peak ~192.1 MiB
    char* wsb = (char*)d_ws;
    __hip_bfloat16* gF  = (__hip_bfloat16*)(wsb);                 // 16384*1536 bf16 = 50,331,648 B
    __hip_bfloat16* gB  = (__hip_bfloat16*)(wsb +  50331648);     // 50,331,648 B
    float*          seq = (float*)(wsb + 100663296);              // 16384*768 f32  = 50,331,648 B
    float*          hct = (float*)(wsb + 150994944);              // 16384*768 f32  = 50,331,648 B
    float*          hbf = (float*)(wsb + 201326592);              // 24,576 floats
    unsigned int*   cnt = (unsigned int*)(wsb + 201425152);       // 64 uints
    float*          h2  = (float*)(wsb);                          // 16384*384 f32, aliases gF (dead)
    float*          y1  = (float*)(wsb +  50331648);              // 16384*256 f32, aliases gB (dead)
    float*          y2  = (float*)(wsb +  50331648 + 16777216);   // 16384*96 f32

    const int M = BATCH * S_LEN;   // 16384
    dim3 tb(256);

    // ---- layer 1 ----
    zero_kernel<<<dim3(96), tb, 0, stream>>>(hbf, cnt);
    gemm_nt<0, __hip_bfloat16><<<dim3(M/128, 24), tb, 0, stream>>>(x, DIN, l1_Wih_f, l1_b_f, gF, 1536, M, 1536, DIN);
    gemm_nt<0, __hip_bfloat16><<<dim3(M/128, 24), tb, 0, stream>>>(x, DIN, l1_Wih_b, l1_b_b, gB, 1536, M, 1536, DIN);
    lstm_scan<<<dim3(2*NBLK), dim3(512), 0, stream>>>(gF, gB, l1_Whh_f, l1_Whh_b, seq, hbf, cnt);

    // ---- fc1 + windowed attention -> h_cat ----
    gemm_nt<0, float><<<dim3(M/128, 6), tb, 0, stream>>>(seq, 768, fc1_W, fc1_b, hct, 768, M, 384, 768);
    attn_win<<<dim3(M), tb, 0, stream>>>(hct, attn_W, hct, wsz);

    // ---- layer 2 ----
    zero_kernel<<<dim3(96), tb, 0, stream>>>(hbf, cnt);
    gemm_nt<0, __hip_bfloat16><<<dim3(M/128, 24), tb, 0, stream>>>(hct, 768, l2_Wih_f, l2_b_f, gF, 1536, M, 1536, 768);
    gemm_nt<0, __hip_bfloat16><<<dim3(M/128, 24), tb, 0, stream>>>(hct, 768, l2_Wih_b, l2_b_b, gB, 1536, M, 1536, 768);
    lstm_scan<<<dim3(2*NBLK), dim3(512), 0, stream>>>(gF, gB, l2_Whh_f, l2_Whh_b, seq, hbf, cnt);

    // ---- head: fc1 again, then MLP ----
    gemm_nt<0, float><<<dim3(M/128, 6), tb, 0, stream>>>(seq, 768, fc1_W, fc1_b, h2, 384, M, 384, 768);
    gemm_nt<1, float><<<dim3(M/128, 4), tb, 0, stream>>>(h2, 384, w1, b1, y1, 256, M, 256, 384);
    gemm_nt<1, float><<<dim3(M/128, 2), tb, 0, stream>>>(y1, 256, w2, b2, y2, 96, M, 96, 256);
    final_dot<<<dim3(M/256), tb, 0, stream>>>(y2, w3, b3, (float*)d_out);
}

// Round 3
// 23733.411 us; speedup vs baseline: 1.4450x; 1.4450x over previous
//
#include <hip/hip_runtime.h>
#include <hip/hip_bf16.h>
#include <type_traits>

#define S_LEN 1024
#define BATCH 16
#define HID   384
#define DIN   768

// ---------------- LSTM scan configuration ----------------
#define NBLK 48                // blocks per direction (96 total, all resident)
#define UBLK 8                 // hidden units per block (48*8 = 384)
#define HSTR 388               // LDS row stride for h (388%32==4 -> 2-way worst aliasing)

__device__ __forceinline__ float sigf(float x)     { return 1.f/(1.f + __expf(-x)); }
__device__ __forceinline__ float tanhfast(float x) { return 1.f - 2.f/(__expf(2.f*x) + 1.f); }

// ---------------- zero init for h-exchange buffers + barrier counters ----------------
__global__ void zero_kernel(float* hbuf, unsigned int* cnt)
{
    int i = blockIdx.x * blockDim.x + threadIdx.x;
    if (i < 2*2*BATCH*HID) hbuf[i] = 0.f;   // 24576 floats
    if (i < 64) cnt[i] = 0u;
}

// ---------------- generic fp32 GEMM: C = act(A @ W^T + bias), OT output ----------------
// A [M,K] ldA, W [N,K], C [M,N] ldC.  BM=128 BN=64 BK=16, 256 threads.
template<int RELU, typename OT>
__global__ __launch_bounds__(256) void gemm_nt(
    const float* __restrict__ A, int ldA,
    const float* __restrict__ W,
    const float* __restrict__ bias,
    OT* __restrict__ C, int ldC,
    int M, int N, int K)
{
    __shared__ float As[16][132];
    __shared__ float Ws[16][68];
    const int tid = threadIdx.x;
    const int m0 = blockIdx.x * 128;
    const int n0 = blockIdx.y * 64;
    const int tm = (tid & 15) * 8;
    const int tn = (tid >> 4) * 4;

    float acc[8][4];
    #pragma unroll
    for (int i = 0; i < 8; i++)
        #pragma unroll
        for (int j = 0; j < 4; j++) acc[i][j] = 0.f;

    const int lrow = tid >> 2;          // 0..63
    const int lk   = (tid & 3) * 4;     // 0,4,8,12

    for (int k0 = 0; k0 < K; k0 += 16) {
        #pragma unroll
        for (int p = 0; p < 2; p++) {
            const int r = lrow + p * 64;
            const float4 av = *(const float4*)(A + (size_t)(m0 + r) * ldA + k0 + lk);
            As[lk+0][r] = av.x; As[lk+1][r] = av.y; As[lk+2][r] = av.z; As[lk+3][r] = av.w;
        }
        {
            float4 wv = make_float4(0.f, 0.f, 0.f, 0.f);
            if (n0 + lrow < N) wv = *(const float4*)(W + (size_t)(n0 + lrow) * K + k0 + lk);
            Ws[lk+0][lrow] = wv.x; Ws[lk+1][lrow] = wv.y; Ws[lk+2][lrow] = wv.z; Ws[lk+3][lrow] = wv.w;
        }
        __syncthreads();
        #pragma unroll
        for (int k = 0; k < 16; k++) {
            const float4 a0 = *(const float4*)&As[k][tm];
            const float4 a1 = *(const float4*)&As[k][tm + 4];
            const float4 bv = *(const float4*)&Ws[k][tn];
            const float am[8] = {a0.x, a0.y, a0.z, a0.w, a1.x, a1.y, a1.z, a1.w};
            const float bb[4] = {bv.x, bv.y, bv.z, bv.w};
            #pragma unroll
            for (int i = 0; i < 8; i++)
                #pragma unroll
                for (int j = 0; j < 4; j++) acc[i][j] += am[i] * bb[j];
        }
        __syncthreads();
    }

    #pragma unroll
    for (int i = 0; i < 8; i++) {
        const int m = m0 + tm + i;
        #pragma unroll
        for (int j = 0; j < 4; j++) {
            const int n = n0 + tn + j;
            if (n < N) {
                float v = acc[i][j] + bias[n];
                if (RELU) v = fmaxf(v, 0.f);
                if constexpr (std::is_same_v<OT, __hip_bfloat16>)
                    C[(size_t)m * ldC + n] = __float2bfloat16(v);
                else
                    C[(size_t)m * ldC + n] = v;
            }
        }
    }
}

// ---------------- persistent LSTM scan (one layer, both directions) ----------------
// grid = 96 blocks (48 fwd + 48 bwd), 512 threads, 25 KB static LDS.
// Thread (b = tid&15, g = (tid>>4)&3, u = tid>>6) computes the FULL 384-wide dot
// for gate-row (g, u0+u) and batch b. Gate gather to g==0 lanes via 3 shfls.
// h exchange via agent-scope atomics (bypass L1/L2, coherent at IC) — NO fences:
// __syncthreads' vmcnt-drain orders data stores before the counter fetch-add.
__global__ __launch_bounds__(512) void lstm_scan(
    const __hip_bfloat16* __restrict__ gatesF, const __hip_bfloat16* __restrict__ gatesB,
    const float* __restrict__ WhhF,            const float* __restrict__ WhhB,
    float* __restrict__ out, float* hbuf, unsigned int* cnt)
{
    __shared__ float hl[BATCH * HSTR];         // staged h_prev, fp32

    const int blk = blockIdx.x;
    const int dir = blk / NBLK;
    const int u0  = (blk % NBLK) * UBLK;
    const __hip_bfloat16* gates = dir ? gatesB : gatesF;
    const float* Whh = dir ? WhhB : WhhF;
    float* hbG = hbuf + dir * (2 * BATCH * HID);     // [2 slots][16][384]
    unsigned int* bar = cnt + dir * 32;              // separate 128B lines

    const int tid  = threadIdx.x;
    const int b    = tid & 15;
    const int g    = (tid >> 4) & 3;
    const int u    = tid >> 6;                 // 0..7 == wave index
    const int lane = tid & 63;
    const int u_glob = u0 + u;
    const bool owner = (g == 0);

    // this thread's weight row (one gate-row, full k)
    const float* wp = Whh + ((size_t)g * HID + u_glob) * HID;
    // this thread's gate pre-activation stream (one bf16 per step)
    const __hip_bfloat16* gp =
        gates + (size_t)b * (S_LEN * 4 * HID) + (size_t)g * HID + u_glob;

    // precompute h-staging LDS destinations (t-invariant): 3072 u64 = 512 thr x 6
    int dst_off[6];
    #pragma unroll
    for (int j = 0; j < 6; j++) {
        const int f = 2 * (tid + 512 * j);      // flat float index 0..6142
        const int bb = f / 384;
        dst_off[j] = bb * HSTR + (f - bb * 384);
    }
    const int hrow = b * HSTR;

    float c_state = 0.f;

    for (int t = 0; t < S_LEN; t++) {
        const int tt = dir ? (S_LEN - 1 - t) : t;

        // prefetch this step's gate pre-activation (1 bf16 per thread)
        const float gx = __bfloat162float(gp[(size_t)tt * (4 * HID)]);

        // stage h_prev from IC-coherent buffer into LDS (8B agent-scope atomic loads)
        {
            const unsigned long long* src =
                (const unsigned long long*)(hbG + (t & 1) * (BATCH * HID));
            #pragma unroll
            for (int j = 0; j < 6; j++) {
                unsigned long long q = __hip_atomic_load(src + tid + 512 * j,
                                        __ATOMIC_RELAXED, __HIP_MEMORY_SCOPE_AGENT);
                union { unsigned long long q; float2 f; } cv; cv.q = q;
                *(float2*)(hl + dst_off[j]) = cv.f;
            }
        }
        __syncthreads();

        // full 384-wide dot: weight row from L1/L2, h from LDS (16 uniq addr/wave)
        float a = gx;
        #pragma unroll 8
        for (int m = 0; m < 96; m++) {
            const float4 h4 = *(const float4*)(hl + hrow + 4 * m);
            const float4 w4 = *(const float4*)(wp + 4 * m);
            a += h4.x*w4.x + h4.y*w4.y + h4.z*w4.z + h4.w*w4.w;
        }

        // gather all 4 gates of (u,b) into the g==0 lane
        const int bl = lane & 15;
        const float xf = __shfl(a, bl | 16, 64);
        const float xg = __shfl(a, bl | 32, 64);
        const float xo = __shfl(a, bl | 48, 64);

        if (owner) {
            const float ii = sigf(a), ff = sigf(xf), gg = tanhfast(xg), oo = sigf(xo);
            c_state = ff * c_state + ii * gg;
            const float hn = oo * tanhfast(c_state);
            // coherent (IC) store for next-step exchange
            __hip_atomic_store(hbG + ((t + 1) & 1) * (BATCH * HID) + b * HID + u_glob,
                               hn, __ATOMIC_RELAXED, __HIP_MEMORY_SCOPE_AGENT);
            // plain store for downstream kernels (dispatch-end release covers it)
            out[((size_t)(b * S_LEN + tt)) * (2 * HID) + dir * HID + u_glob] = hn;
        }

        __syncthreads();   // vmcnt(0) drain: all waves' h stores committed at IC
        if (tid == 0) {
            __hip_atomic_fetch_add(bar, 1u, __ATOMIC_RELAXED, __HIP_MEMORY_SCOPE_AGENT);
            const unsigned int target = (unsigned int)(NBLK * (t + 1));
            long guard = 0;
            while (__hip_atomic_load(bar, __ATOMIC_RELAXED, __HIP_MEMORY_SCOPE_AGENT) < target
                   && guard < 200000000L) { __builtin_amdgcn_s_sleep(1); ++guard; }
        }
        __syncthreads();
    }
}

// ---------------- windowed attention ----------------
// score_j = (h_i*w3 + w2) . h_j   (s1[i] and attn_b are constant over j -> cancel in softmax)
__global__ __launch_bounds__(256) void attn_win(
    const float* __restrict__ hcat,   // [16][1024][768], h in cols 0..383
    const float* __restrict__ attnW,  // [1152] = w1|w2|w3
    float* __restrict__ ocat,         // same buffer, writes cols 384..767
    const int* __restrict__ wsz_p)
{
    __shared__ float q[HID];
    __shared__ float sc[96];
    __shared__ float p[96];
    const int blk = blockIdx.x;
    const int b = blk >> 10, i = blk & 1023;
    const int W = *wsz_p;
    const int jlo = max(i - W, 0), jhi = min(i + W, S_LEN - 1);
    const int nj = jhi - jlo + 1;
    const int tid = threadIdx.x;
    const float* hrow = hcat + (size_t)b * S_LEN * 768;

    if (tid < 96) {
        const float4 hv = *(const float4*)(hrow + (size_t)i * 768 + tid * 4);
        const float4 w3 = *(const float4*)(attnW + 768 + tid * 4);
        const float4 w2 = *(const float4*)(attnW + 384 + tid * 4);
        float4 r;
        r.x = hv.x*w3.x + w2.x; r.y = hv.y*w3.y + w2.y;
        r.z = hv.z*w3.z + w2.z; r.w = hv.w*w3.w + w2.w;
        *(float4*)(q + tid * 4) = r;
    }
    __syncthreads();

    const int wv = tid >> 6, lane = tid & 63;
    for (int jj = wv; jj < nj; jj += 4) {
        const float* hj = hrow + (size_t)(jlo + jj) * 768;
        float s = 0.f;
        #pragma unroll
        for (int c = 0; c < 6; c++) { const int d = lane + 64*c; s += q[d] * hj[d]; }
        #pragma unroll
        for (int st = 1; st < 64; st <<= 1) s += __shfl_xor(s, st, 64);
        if (lane == 0) sc[jj] = s;
    }
    __syncthreads();

    if (tid < 64) {
        float v1 = (tid < nj) ? sc[tid] : -3e38f;
        float v2 = (64 + tid < nj) ? sc[64 + tid] : -3e38f;
        float m = fmaxf(v1, v2);
        #pragma unroll
        for (int st = 1; st < 64; st <<= 1) m = fmaxf(m, __shfl_xor(m, st, 64));
        float e1 = (tid < nj) ? __expf(v1 - m) : 0.f;
        float e2 = (64 + tid < nj) ? __expf(v2 - m) : 0.f;
        float sum = e1 + e2;
        #pragma unroll
        for (int st = 1; st < 64; st <<= 1) sum += __shfl_xor(sum, st, 64);
        const float inv = 1.f / sum;
        if (tid < nj) p[tid] = e1 * inv;
        if (64 + tid < nj) p[64 + tid] = e2 * inv;
    }
    __syncthreads();

    if (tid < 192) {
        const int d = tid * 2;
        float s0 = 0.f, s1 = 0.f;
        for (int jj = 0; jj < nj; jj++) {
            const float* hj = hrow + (size_t)(jlo + jj) * 768 + d;
            const float pj = p[jj];
            s0 += pj * hj[0]; s1 += pj * hj[1];
        }
        float* o = ocat + (size_t)b * S_LEN * 768 + (size_t)i * 768 + 384 + d;
        o[0] = s0; o[1] = s1;
    }
}

// ---------------- final 96 -> 1 dot ----------------
__global__ __launch_bounds__(256) void final_dot(
    const float* __restrict__ y2, const float* __restrict__ W3,
    const float* __restrict__ b3, float* __restrict__ outp)
{
    __shared__ float w[96];
    const int tid = threadIdx.x;
    if (tid < 96) w[tid] = W3[tid];
    __syncthreads();
    const int r = blockIdx.x * 256 + tid;
    const float* row = y2 + (size_t)r * 96;
    float s = 0.f;
    #pragma unroll
    for (int c = 0; c < 24; c++) {
        const float4 v = ((const float4*)row)[c];
        s += v.x*w[c*4] + v.y*w[c*4+1] + v.z*w[c*4+2] + v.w*w[c*4+3];
    }
    outp[r] = s + b3[0];
}

// ---------------- launcher ----------------
extern "C" void kernel_launch(void* const* d_in, const int* in_sizes, int n_in,
                              void* d_out, int out_size, void* d_ws, size_t ws_size,
                              hipStream_t stream)
{
    const float* x        = (const float*)d_in[0];
    const float* l1_Wih_f = (const float*)d_in[1];
    const float* l1_Whh_f = (const float*)d_in[2];
    const float* l1_b_f   = (const float*)d_in[3];
    const float* l1_Wih_b = (const float*)d_in[4];
    const float* l1_Whh_b = (const float*)d_in[5];
    const float* l1_b_b   = (const float*)d_in[6];
    const float* l2_Wih_f = (const float*)d_in[7];
    const float* l2_Whh_f = (const float*)d_in[8];
    const float* l2_b_f   = (const float*)d_in[9];
    const float* l2_Wih_b = (const float*)d_in[10];
    const float* l2_Whh_b = (const float*)d_in[11];
    const float* l2_b_b   = (const float*)d_in[12];
    const float* fc1_W    = (const float*)d_in[13];
    const float* fc1_b    = (const float*)d_in[14];
    const float* attn_W   = (const float*)d_in[15];
    /* d_in[16] attn_b: cancels in softmax */
    const float* w1       = (const float*)d_in[17];
    const float* b1       = (const float*)d_in[18];
    const float* w2       = (const float*)d_in[19];
    const float* b2       = (const float*)d_in[20];
    const float* w3       = (const float*)d_in[21];
    const float* b3       = (const float*)d_in[22];
    const int*   wsz      = (const int*)d_in[23];

    // workspace layout (bytes), peak ~192.1 MiB
    char* wsb = (char*)d_ws;
    __hip_bfloat16* gF  = (__hip_bfloat16*)(wsb);                 // 16384*1536 bf16 = 50,331,648 B
    __hip_bfloat16* gB  = (__hip_bfloat16*)(wsb +  50331648);     // 50,331,648 B
    float*          seq = (float*)(wsb + 100663296);              // 16384*768 f32  = 50,331,648 B
    float*          hct = (float*)(wsb + 150994944);              // 16384*768 f32  = 50,331,648 B
    float*          hbf = (float*)(wsb + 201326592);              // 24,576 floats
    unsigned int*   cnt = (unsigned int*)(wsb + 201425152);       // 64 uints
    float*          h2  = (float*)(wsb);                          // 16384*384 f32, aliases gF (dead)
    float*          y1  = (float*)(wsb +  50331648);              // 16384*256 f32, aliases gB (dead)
    float*          y2  = (float*)(wsb +  50331648 + 16777216);   // 16384*96 f32

    const int M = BATCH * S_LEN;   // 16384
    dim3 tb(256);

    // ---- layer 1 ----
    zero_kernel<<<dim3(96), tb, 0, stream>>>(hbf, cnt);
    gemm_nt<0, __hip_bfloat16><<<dim3(M/128, 24), tb, 0, stream>>>(x, DIN, l1_Wih_f, l1_b_f, gF, 1536, M, 1536, DIN);
    gemm_nt<0, __hip_bfloat16><<<dim3(M/128, 24), tb, 0, stream>>>(x, DIN, l1_Wih_b, l1_b_b, gB, 1536, M, 1536, DIN);
    lstm_scan<<<dim3(2*NBLK), dim3(512), 0, stream>>>(gF, gB, l1_Whh_f, l1_Whh_b, seq, hbf, cnt);

    // ---- fc1 + windowed attention -> h_cat ----
    gemm_nt<0, float><<<dim3(M/128, 6), tb, 0, stream>>>(seq, 768, fc1_W, fc1_b, hct, 768, M, 384, 768);
    attn_win<<<dim3(M), tb, 0, stream>>>(hct, attn_W, hct, wsz);

    // ---- layer 2 ----
    zero_kernel<<<dim3(96), tb, 0, stream>>>(hbf, cnt);
    gemm_nt<0, __hip_bfloat16><<<dim3(M/128, 24), tb, 0, stream>>>(hct, 768, l2_Wih_f, l2_b_f, gF, 1536, M, 1536, 768);
    gemm_nt<0, __hip_bfloat16><<<dim3(M/128, 24), tb, 0, stream>>>(hct, 768, l2_Wih_b, l2_b_b, gB, 1536, M, 1536, 768);
    lstm_scan<<<dim3(2*NBLK), dim3(512), 0, stream>>>(gF, gB, l2_Whh_f, l2_Whh_b, seq, hbf, cnt);

    // ---- head: fc1 again, then MLP ----
    gemm_nt<0, float><<<dim3(M/128, 6), tb, 0, stream>>>(seq, 768, fc1_W, fc1_b, h2, 384, M, 384, 768);
    gemm_nt<1, float><<<dim3(M/128, 4), tb, 0, stream>>>(h2, 384, w1, b1, y1, 256, M, 256, 384);
    gemm_nt<1, float><<<dim3(M/128, 2), tb, 0, stream>>>(y1, 256, w2, b2, y2, 96, M, 96, 256);
    final_dot<<<dim3(M/256), tb, 0, stream>>>(y2, w3, b3, (float*)d_out);
}

// Round 4
// 7999.055 us; speedup vs baseline: 4.2873x; 2.9670x over previous
//
#include <hip/hip_runtime.h>
#include <hip/hip_bf16.h>
#include <type_traits>

#define S_LEN 1024
#define BATCH 16
#define HID   384
#define DIN   768

// ---------------- LSTM scan configuration ----------------
// 32 groups = (dir, batch); GRP member blocks per group; UPB units per member.
#define GRP 24
#define UPB 16

__device__ __forceinline__ float sigf(float x)     { return 1.f/(1.f + __expf(-x)); }
__device__ __forceinline__ float tanhfast(float x) { return 1.f - 2.f/(__expf(2.f*x) + 1.f); }

// ---------------- zero init: h-exchange buffers + per-group flags ----------------
__global__ void zero_kernel(float* hbuf, unsigned int* flags, int zf)
{
    int i = blockIdx.x * blockDim.x + threadIdx.x;
    if (i < 32*2*HID) hbuf[i] = 0.f;          // 24576 floats
    if (zf && i < 32*64) flags[i] = 0u;       // 2048 u32
}

// ---------------- generic fp32 GEMM: C = act(A @ W^T + bias), OT output ----------------
// A [M,K] ldA, W [N,K], C [M,N] ldC.  BM=128 BN=64 BK=16, 256 threads.
template<int RELU, typename OT>
__global__ __launch_bounds__(256) void gemm_nt(
    const float* __restrict__ A, int ldA,
    const float* __restrict__ W,
    const float* __restrict__ bias,
    OT* __restrict__ C, int ldC,
    int M, int N, int K)
{
    __shared__ float As[16][132];
    __shared__ float Ws[16][68];
    const int tid = threadIdx.x;
    const int m0 = blockIdx.x * 128;
    const int n0 = blockIdx.y * 64;
    const int tm = (tid & 15) * 8;
    const int tn = (tid >> 4) * 4;

    float acc[8][4];
    #pragma unroll
    for (int i = 0; i < 8; i++)
        #pragma unroll
        for (int j = 0; j < 4; j++) acc[i][j] = 0.f;

    const int lrow = tid >> 2;          // 0..63
    const int lk   = (tid & 3) * 4;     // 0,4,8,12

    for (int k0 = 0; k0 < K; k0 += 16) {
        #pragma unroll
        for (int p = 0; p < 2; p++) {
            const int r = lrow + p * 64;
            const float4 av = *(const float4*)(A + (size_t)(m0 + r) * ldA + k0 + lk);
            As[lk+0][r] = av.x; As[lk+1][r] = av.y; As[lk+2][r] = av.z; As[lk+3][r] = av.w;
        }
        {
            float4 wv = make_float4(0.f, 0.f, 0.f, 0.f);
            if (n0 + lrow < N) wv = *(const float4*)(W + (size_t)(n0 + lrow) * K + k0 + lk);
            Ws[lk+0][lrow] = wv.x; Ws[lk+1][lrow] = wv.y; Ws[lk+2][lrow] = wv.z; Ws[lk+3][lrow] = wv.w;
        }
        __syncthreads();
        #pragma unroll
        for (int k = 0; k < 16; k++) {
            const float4 a0 = *(const float4*)&As[k][tm];
            const float4 a1 = *(const float4*)&As[k][tm + 4];
            const float4 bv = *(const float4*)&Ws[k][tn];
            const float am[8] = {a0.x, a0.y, a0.z, a0.w, a1.x, a1.y, a1.z, a1.w};
            const float bb[4] = {bv.x, bv.y, bv.z, bv.w};
            #pragma unroll
            for (int i = 0; i < 8; i++)
                #pragma unroll
                for (int j = 0; j < 4; j++) acc[i][j] += am[i] * bb[j];
        }
        __syncthreads();
    }

    #pragma unroll
    for (int i = 0; i < 8; i++) {
        const int m = m0 + tm + i;
        #pragma unroll
        for (int j = 0; j < 4; j++) {
            const int n = n0 + tn + j;
            if (n < N) {
                float v = acc[i][j] + bias[n];
                if (RELU) v = fmaxf(v, 0.f);
                if constexpr (std::is_same_v<OT, __hip_bfloat16>)
                    C[(size_t)m * ldC + n] = __float2bfloat16(v);
                else
                    C[(size_t)m * ldC + n] = v;
            }
        }
    }
}

// ---------------- persistent LSTM scan (one layer, both directions) ----------------
// grid = 768 blocks = 32 groups (dir,batch) x 24 members; 256 threads; ~1.6KB LDS.
// Member m owns units [m*16, m*16+16). Thread (rr=tid>>4, ss=tid&15): unit rr,
// k-slice [ss*24, ss*24+24). Whh slice (4 gates x 24 taps) lives in REGISTERS (fp32).
// Per step: poll group flags -> stage 1.5KB h via IC-coherent atomics -> dot ->
// shfl-reduce over ss -> owner (ss==0) does LSTM cell math -> publish h + flag.
// Flags: per-member single-writer, 2-slot rotation, monotone epoch-tagged values.
__global__ __launch_bounds__(256, 3) void lstm_scan(
    const __hip_bfloat16* __restrict__ gatesF, const __hip_bfloat16* __restrict__ gatesB,
    const float* __restrict__ WhhF,            const float* __restrict__ WhhB,
    float* __restrict__ out, float* hbuf, unsigned int* flags, int epoch)
{
    __shared__ float hl[HID];

    const int blk = blockIdx.x;
    const int g   = blk & 31;          // group: all members share blk%8 -> same XCD (perf hint only)
    const int m   = blk >> 5;          // member 0..23
    const int dir = g >> 4;
    const int b   = g & 15;
    const int u0  = m * UPB;

    const __hip_bfloat16* gates = dir ? gatesB : gatesF;
    const float* Whh = dir ? WhhB : WhhF;
    float* hbG = hbuf + g * (2 * HID);           // [2 slots][384]
    unsigned int* flg = flags + g * 64;          // [2 slots][32]

    const int tid = threadIdx.x;
    const int rr  = tid >> 4;          // local unit 0..15
    const int ss  = tid & 15;          // k-part
    const int ug  = u0 + rr;
    const bool owner = (ss == 0);
    const int k0 = ss * 24;

    // one-time: weight slice into registers (full fp32 — no precision loss)
    float w[4][24];
    #pragma unroll
    for (int gt = 0; gt < 4; gt++) {
        const float* wp = Whh + ((size_t)gt * HID + ug) * HID + k0;
        #pragma unroll
        for (int j = 0; j < 6; j++) {
            const float4 v = *(const float4*)(wp + 4 * j);
            w[gt][4*j+0] = v.x; w[gt][4*j+1] = v.y;
            w[gt][4*j+2] = v.z; w[gt][4*j+3] = v.w;
        }
    }

    float c_state = 0.f;
    const unsigned tbase = (unsigned)epoch * 1024u;

    for (int t = 0; t < S_LEN; t++) {
        const int tt = dir ? (S_LEN - 1 - t) : t;

        // issue this step's gate-preact loads early (independent of the poll)
        float gx0 = 0.f, gx1 = 0.f, gx2 = 0.f, gx3 = 0.f;
        if (owner) {
            const __hip_bfloat16* gp = gates + ((size_t)(b * S_LEN + tt)) * (4 * HID) + ug;
            gx0 = __bfloat162float(gp[0]);
            gx1 = __bfloat162float(gp[HID]);
            gx2 = __bfloat162float(gp[2 * HID]);
            gx3 = __bfloat162float(gp[3 * HID]);
        }

        // wait until all 24 members published h_{t-1} (wave 0 only; single-writer flags)
        if (t > 0 && tid < 64) {
            const unsigned tgt = tbase + (unsigned)t;
            const unsigned* fp = flg + ((t + 1) & 1) * 32;
            bool ok = (tid >= GRP);
            long guard = 0;
            while (true) {
                if (!ok) ok = (__hip_atomic_load(fp + tid, __ATOMIC_RELAXED,
                                                 __HIP_MEMORY_SCOPE_AGENT) >= tgt);
                if (__ballot(ok) == 0xFFFFFFFFFFFFFFFFull) break;
                if (++guard > (1L << 24)) break;   // hang -> wrong answer, not deadlock
                __builtin_amdgcn_s_sleep(1);
            }
        }
        __syncthreads();

        // stage h_{t-1} (1.5KB) from IC-coherent slot into LDS
        if (tid < 192) {
            const unsigned long long q = __hip_atomic_load(
                (const unsigned long long*)(hbG + ((t + 1) & 1) * HID) + tid,
                __ATOMIC_RELAXED, __HIP_MEMORY_SCOPE_AGENT);
            union { unsigned long long u; float2 f; } cv; cv.u = q;
            *(float2*)(hl + 2 * tid) = cv.f;
        }
        __syncthreads();

        // 4 gate dots over this thread's 24-tap k-slice (weights in regs)
        float a0 = 0.f, a1 = 0.f, a2 = 0.f, a3 = 0.f;
        #pragma unroll
        for (int j6 = 0; j6 < 6; j6++) {
            const float4 h4 = *(const float4*)(hl + k0 + 4 * j6);
            const float hh[4] = {h4.x, h4.y, h4.z, h4.w};
            #pragma unroll
            for (int e = 0; e < 4; e++) {
                const int j = 4 * j6 + e;
                a0 += w[0][j] * hh[e];
                a1 += w[1][j] * hh[e];
                a2 += w[2][j] * hh[e];
                a3 += w[3][j] * hh[e];
            }
        }
        // reduce over ss (lane bits 0..3)
        a0 += __shfl_xor(a0, 1, 64); a0 += __shfl_xor(a0, 2, 64);
        a0 += __shfl_xor(a0, 4, 64); a0 += __shfl_xor(a0, 8, 64);
        a1 += __shfl_xor(a1, 1, 64); a1 += __shfl_xor(a1, 2, 64);
        a1 += __shfl_xor(a1, 4, 64); a1 += __shfl_xor(a1, 8, 64);
        a2 += __shfl_xor(a2, 1, 64); a2 += __shfl_xor(a2, 2, 64);
        a2 += __shfl_xor(a2, 4, 64); a2 += __shfl_xor(a2, 8, 64);
        a3 += __shfl_xor(a3, 1, 64); a3 += __shfl_xor(a3, 2, 64);
        a3 += __shfl_xor(a3, 4, 64); a3 += __shfl_xor(a3, 8, 64);

        if (owner) {
            const float ii = sigf(a0 + gx0);
            const float ff = sigf(a1 + gx1);
            const float gg = tanhfast(a2 + gx2);
            const float oo = sigf(a3 + gx3);
            c_state = ff * c_state + ii * gg;
            const float hn = oo * tanhfast(c_state);
            // publish h_t (IC-coherent) + plain store for downstream kernels
            __hip_atomic_store(hbG + (t & 1) * HID + ug, hn,
                               __ATOMIC_RELAXED, __HIP_MEMORY_SCOPE_AGENT);
            out[((size_t)(b * S_LEN + tt)) * (2 * HID) + dir * HID + ug] = hn;
        }

        __syncthreads();   // vmcnt(0) drain: all owner stores committed before flag
        if (tid == 0)
            __hip_atomic_store(flg + (t & 1) * 32 + m, tbase + (unsigned)t + 1u,
                               __ATOMIC_RELAXED, __HIP_MEMORY_SCOPE_AGENT);
    }
}

// ---------------- windowed attention ----------------
// score_j = (h_i*w3 + w2) . h_j   (s1[i] and attn_b are constant over j -> cancel in softmax)
__global__ __launch_bounds__(256) void attn_win(
    const float* __restrict__ hcat,   // [16][1024][768], h in cols 0..383
    const float* __restrict__ attnW,  // [1152] = w1|w2|w3
    float* __restrict__ ocat,         // same buffer, writes cols 384..767
    const int* __restrict__ wsz_p)
{
    __shared__ float q[HID];
    __shared__ float sc[96];
    __shared__ float p[96];
    const int blk = blockIdx.x;
    const int b = blk >> 10, i = blk & 1023;
    const int W = *wsz_p;
    const int jlo = max(i - W, 0), jhi = min(i + W, S_LEN - 1);
    const int nj = jhi - jlo + 1;
    const int tid = threadIdx.x;
    const float* hrow = hcat + (size_t)b * S_LEN * 768;

    if (tid < 96) {
        const float4 hv = *(const float4*)(hrow + (size_t)i * 768 + tid * 4);
        const float4 w3 = *(const float4*)(attnW + 768 + tid * 4);
        const float4 w2 = *(const float4*)(attnW + 384 + tid * 4);
        float4 r;
        r.x = hv.x*w3.x + w2.x; r.y = hv.y*w3.y + w2.y;
        r.z = hv.z*w3.z + w2.z; r.w = hv.w*w3.w + w2.w;
        *(float4*)(q + tid * 4) = r;
    }
    __syncthreads();

    const int wv = tid >> 6, lane = tid & 63;
    for (int jj = wv; jj < nj; jj += 4) {
        const float* hj = hrow + (size_t)(jlo + jj) * 768;
        float s = 0.f;
        #pragma unroll
        for (int c = 0; c < 6; c++) { const int d = lane + 64*c; s += q[d] * hj[d]; }
        #pragma unroll
        for (int st = 1; st < 64; st <<= 1) s += __shfl_xor(s, st, 64);
        if (lane == 0) sc[jj] = s;
    }
    __syncthreads();

    if (tid < 64) {
        float v1 = (tid < nj) ? sc[tid] : -3e38f;
        float v2 = (64 + tid < nj) ? sc[64 + tid] : -3e38f;
        float m = fmaxf(v1, v2);
        #pragma unroll
        for (int st = 1; st < 64; st <<= 1) m = fmaxf(m, __shfl_xor(m, st, 64));
        float e1 = (tid < nj) ? __expf(v1 - m) : 0.f;
        float e2 = (64 + tid < nj) ? __expf(v2 - m) : 0.f;
        float sum = e1 + e2;
        #pragma unroll
        for (int st = 1; st < 64; st <<= 1) sum += __shfl_xor(sum, st, 64);
        const float inv = 1.f / sum;
        if (tid < nj) p[tid] = e1 * inv;
        if (64 + tid < nj) p[64 + tid] = e2 * inv;
    }
    __syncthreads();

    if (tid < 192) {
        const int d = tid * 2;
        float s0 = 0.f, s1 = 0.f;
        for (int jj = 0; jj < nj; jj++) {
            const float* hj = hrow + (size_t)(jlo + jj) * 768 + d;
            const float pj = p[jj];
            s0 += pj * hj[0]; s1 += pj * hj[1];
        }
        float* o = ocat + (size_t)b * S_LEN * 768 + (size_t)i * 768 + 384 + d;
        o[0] = s0; o[1] = s1;
    }
}

// ---------------- final 96 -> 1 dot ----------------
__global__ __launch_bounds__(256) void final_dot(
    const float* __restrict__ y2, const float* __restrict__ W3,
    const float* __restrict__ b3, float* __restrict__ outp)
{
    __shared__ float w[96];
    const int tid = threadIdx.x;
    if (tid < 96) w[tid] = W3[tid];
    __syncthreads();
    const int r = blockIdx.x * 256 + tid;
    const float* row = y2 + (size_t)r * 96;
    float s = 0.f;
    #pragma unroll
    for (int c = 0; c < 24; c++) {
        const float4 v = ((const float4*)row)[c];
        s += v.x*w[c*4] + v.y*w[c*4+1] + v.z*w[c*4+2] + v.w*w[c*4+3];
    }
    outp[r] = s + b3[0];
}

// ---------------- launcher ----------------
extern "C" void kernel_launch(void* const* d_in, const int* in_sizes, int n_in,
                              void* d_out, int out_size, void* d_ws, size_t ws_size,
                              hipStream_t stream)
{
    const float* x        = (const float*)d_in[0];
    const float* l1_Wih_f = (const float*)d_in[1];
    const float* l1_Whh_f = (const float*)d_in[2];
    const float* l1_b_f   = (const float*)d_in[3];
    const float* l1_Wih_b = (const float*)d_in[4];
    const float* l1_Whh_b = (const float*)d_in[5];
    const float* l1_b_b   = (const float*)d_in[6];
    const float* l2_Wih_f = (const float*)d_in[7];
    const float* l2_Whh_f = (const float*)d_in[8];
    const float* l2_b_f   = (const float*)d_in[9];
    const float* l2_Wih_b = (const float*)d_in[10];
    const float* l2_Whh_b = (const float*)d_in[11];
    const float* l2_b_b   = (const float*)d_in[12];
    const float* fc1_W    = (const float*)d_in[13];
    const float* fc1_b    = (const float*)d_in[14];
    const float* attn_W   = (const float*)d_in[15];
    /* d_in[16] attn_b: cancels in softmax */
    const float* w1       = (const float*)d_in[17];
    const float* b1       = (const float*)d_in[18];
    const float* w2       = (const float*)d_in[19];
    const float* b2       = (const float*)d_in[20];
    const float* w3       = (const float*)d_in[21];
    const float* b3       = (const float*)d_in[22];
    const int*   wsz      = (const int*)d_in[23];

    // workspace layout (bytes), peak ~192.1 MiB
    char* wsb = (char*)d_ws;
    __hip_bfloat16* gF  = (__hip_bfloat16*)(wsb);                 // 16384*1536 bf16 = 50,331,648 B
    __hip_bfloat16* gB  = (__hip_bfloat16*)(wsb +  50331648);     // 50,331,648 B
    float*          seq = (float*)(wsb + 100663296);              // 16384*768 f32  = 50,331,648 B
    float*          hct = (float*)(wsb + 150994944);              // 16384*768 f32  = 50,331,648 B
    float*          hbf = (float*)(wsb + 201326592);              // 24,576 floats (32 groups x 2 x 384)
    unsigned int*   flg = (unsigned int*)(wsb + 201424896);       // 2,048 u32 (32 groups x 2 x 32)
    float*          h2  = (float*)(wsb);                          // 16384*384 f32, aliases gF (dead)
    float*          y1  = (float*)(wsb +  50331648);              // 16384*256 f32, aliases gB (dead)
    float*          y2  = (float*)(wsb +  50331648 + 16777216);   // 16384*96 f32

    const int M = BATCH * S_LEN;   // 16384
    dim3 tb(256);

    // ---- layer 1 ----
    zero_kernel<<<dim3(96), tb, 0, stream>>>(hbf, flg, 1);
    gemm_nt<0, __hip_bfloat16><<<dim3(M/128, 24), tb, 0, stream>>>(x, DIN, l1_Wih_f, l1_b_f, gF, 1536, M, 1536, DIN);
    gemm_nt<0, __hip_bfloat16><<<dim3(M/128, 24), tb, 0, stream>>>(x, DIN, l1_Wih_b, l1_b_b, gB, 1536, M, 1536, DIN);
    lstm_scan<<<dim3(768), tb, 0, stream>>>(gF, gB, l1_Whh_f, l1_Whh_b, seq, hbf, flg, 0);

    // ---- fc1 + windowed attention -> h_cat ----
    gemm_nt<0, float><<<dim3(M/128, 6), tb, 0, stream>>>(seq, 768, fc1_W, fc1_b, hct, 768, M, 384, 768);
    attn_win<<<dim3(M), tb, 0, stream>>>(hct, attn_W, hct, wsz);

    // ---- layer 2 ----
    zero_kernel<<<dim3(96), tb, 0, stream>>>(hbf, flg, 0);   // flags carry over via epoch tag
    gemm_nt<0, __hip_bfloat16><<<dim3(M/128, 24), tb, 0, stream>>>(hct, 768, l2_Wih_f, l2_b_f, gF, 1536, M, 1536, 768);
    gemm_nt<0, __hip_bfloat16><<<dim3(M/128, 24), tb, 0, stream>>>(hct, 768, l2_Wih_b, l2_b_b, gB, 1536, M, 1536, 768);
    lstm_scan<<<dim3(768), tb, 0, stream>>>(gF, gB, l2_Whh_f, l2_Whh_b, seq, hbf, flg, 1);

    // ---- head: fc1 again, then MLP ----
    gemm_nt<0, float><<<dim3(M/128, 6), tb, 0, stream>>>(seq, 768, fc1_W, fc1_b, h2, 384, M, 384, 768);
    gemm_nt<1, float><<<dim3(M/128, 4), tb, 0, stream>>>(h2, 384, w1, b1, y1, 256, M, 256, 384);
    gemm_nt<1, float><<<dim3(M/128, 2), tb, 0, stream>>>(y1, 256, w2, b2, y2, 96, M, 96, 256);
    final_dot<<<dim3(M/256), tb, 0, stream>>>(y2, w3, b3, (float*)d_out);
}

// Round 5
// 7996.770 us; speedup vs baseline: 4.2886x; 1.0003x over previous
//
#include <hip/hip_runtime.h>
#include <hip/hip_bf16.h>
#include <type_traits>

#define S_LEN 1024
#define BATCH 16
#define HID   384
#define DIN   768

// ---------------- LSTM scan configuration ----------------
// 32 groups = (dir, batch); GRP member blocks per group; UPB units per member.
#define GRP 24
#define UPB 16

__device__ __forceinline__ float sigf(float x)     { return 1.f/(1.f + __expf(-x)); }
__device__ __forceinline__ float tanhfast(float x) { return 1.f - 2.f/(__expf(2.f*x) + 1.f); }

// ---------------- zero init: packed h-exchange {tag,val} buffer ----------------
// 32 groups x 2 slots x 384 units x 8B = 196,608 B. Must be zeroed every launch
// (harness poisons d_ws with 0xAA -> tags would read as huge -> stale accept).
__global__ void zero_kernel(unsigned long long* hx)
{
    int i = blockIdx.x * blockDim.x + threadIdx.x;
    if (i < 32*2*HID) hx[i] = 0ull;
}

// ---------------- generic fp32 GEMM: C = act(A @ W^T + bias), OT output ----------------
// A [M,K] ldA, W [N,K], C [M,N] ldC.  BM=128 BN=64 BK=16, 256 threads.
template<int RELU, typename OT>
__global__ __launch_bounds__(256) void gemm_nt(
    const float* __restrict__ A, int ldA,
    const float* __restrict__ W,
    const float* __restrict__ bias,
    OT* __restrict__ C, int ldC,
    int M, int N, int K)
{
    __shared__ float As[16][132];
    __shared__ float Ws[16][68];
    const int tid = threadIdx.x;
    const int m0 = blockIdx.x * 128;
    const int n0 = blockIdx.y * 64;
    const int tm = (tid & 15) * 8;
    const int tn = (tid >> 4) * 4;

    float acc[8][4];
    #pragma unroll
    for (int i = 0; i < 8; i++)
        #pragma unroll
        for (int j = 0; j < 4; j++) acc[i][j] = 0.f;

    const int lrow = tid >> 2;          // 0..63
    const int lk   = (tid & 3) * 4;     // 0,4,8,12

    for (int k0 = 0; k0 < K; k0 += 16) {
        #pragma unroll
        for (int p = 0; p < 2; p++) {
            const int r = lrow + p * 64;
            const float4 av = *(const float4*)(A + (size_t)(m0 + r) * ldA + k0 + lk);
            As[lk+0][r] = av.x; As[lk+1][r] = av.y; As[lk+2][r] = av.z; As[lk+3][r] = av.w;
        }
        {
            float4 wv = make_float4(0.f, 0.f, 0.f, 0.f);
            if (n0 + lrow < N) wv = *(const float4*)(W + (size_t)(n0 + lrow) * K + k0 + lk);
            Ws[lk+0][lrow] = wv.x; Ws[lk+1][lrow] = wv.y; Ws[lk+2][lrow] = wv.z; Ws[lk+3][lrow] = wv.w;
        }
        __syncthreads();
        #pragma unroll
        for (int k = 0; k < 16; k++) {
            const float4 a0 = *(const float4*)&As[k][tm];
            const float4 a1 = *(const float4*)&As[k][tm + 4];
            const float4 bv = *(const float4*)&Ws[k][tn];
            const float am[8] = {a0.x, a0.y, a0.z, a0.w, a1.x, a1.y, a1.z, a1.w};
            const float bb[4] = {bv.x, bv.y, bv.z, bv.w};
            #pragma unroll
            for (int i = 0; i < 8; i++)
                #pragma unroll
                for (int j = 0; j < 4; j++) acc[i][j] += am[i] * bb[j];
        }
        __syncthreads();
    }

    #pragma unroll
    for (int i = 0; i < 8; i++) {
        const int m = m0 + tm + i;
        #pragma unroll
        for (int j = 0; j < 4; j++) {
            const int n = n0 + tn + j;
            if (n < N) {
                float v = acc[i][j] + bias[n];
                if (RELU) v = fmaxf(v, 0.f);
                if constexpr (std::is_same_v<OT, __hip_bfloat16>)
                    C[(size_t)m * ldC + n] = __float2bfloat16(v);
                else
                    C[(size_t)m * ldC + n] = v;
            }
        }
    }
}

// ---------------- persistent LSTM scan (one layer, both directions) ----------------
// grid = 768 blocks = 32 groups (dir,batch) x 24 members; 256 threads; 1.5KB LDS.
// Member m owns units [m*16, m*16+16). Thread (rr=tid>>4, ss=tid&15): unit rr,
// k-taps {ss*4 + j*64 + e} (conflict-free b128 LDS reads). Whh slice (4x24) in regs.
// h exchange: packed 8B {tag(hi32), val(lo32)} agent-scope atomics — consumers poll
// the DATA tag directly (no separate flag -> one IC round trip per step).
// 2-slot rotation: slot t&1 written at step t, read at step t+1; a slot is only
// overwritten 2 steps later, which requires all members to have consumed it.
__global__ __launch_bounds__(256, 3) void lstm_scan(
    const __hip_bfloat16* __restrict__ gatesF, const __hip_bfloat16* __restrict__ gatesB,
    const float* __restrict__ WhhF,            const float* __restrict__ WhhB,
    float* __restrict__ out, unsigned long long* hx_all, int epoch)
{
    __shared__ float hl[HID];

    const int blk = blockIdx.x;
    const int g   = blk & 31;          // group (members share blk%8 -> likely same XCD; perf hint only)
    const int m   = blk >> 5;          // member 0..23
    const int dir = g >> 4;
    const int b   = g & 15;
    const int u0  = m * UPB;

    const __hip_bfloat16* gates = dir ? gatesB : gatesF;
    const float* Whh = dir ? WhhB : WhhF;
    unsigned long long* hx = hx_all + g * (2 * HID);   // [2 slots][384] packed

    const int tid = threadIdx.x;
    const int rr  = tid >> 4;          // local unit 0..15
    const int ss  = tid & 15;          // k-part
    const int ug  = u0 + rr;
    const bool owner = (ss == 0);

    // one-time: weight slice into registers (fp32), taps k = ss*4 + j*64 + e
    float w[4][24];
    #pragma unroll
    for (int gt = 0; gt < 4; gt++) {
        const float* wp = Whh + ((size_t)gt * HID + ug) * HID + ss * 4;
        #pragma unroll
        for (int j = 0; j < 6; j++) {
            const float4 v = *(const float4*)(wp + 64 * j);
            w[gt][4*j+0] = v.x; w[gt][4*j+1] = v.y;
            w[gt][4*j+2] = v.z; w[gt][4*j+3] = v.w;
        }
    }

    float c_state = 0.f;
    const unsigned tbase = (unsigned)epoch * 2048u;

    for (int t = 0; t < S_LEN; t++) {
        const int tt = dir ? (S_LEN - 1 - t) : t;

        // issue this step's gate-preact loads early (independent of the poll)
        float gx0 = 0.f, gx1 = 0.f, gx2 = 0.f, gx3 = 0.f;
        if (owner) {
            const __hip_bfloat16* gp = gates + ((size_t)(b * S_LEN + tt)) * (4 * HID) + ug;
            gx0 = __bfloat162float(gp[0]);
            gx1 = __bfloat162float(gp[HID]);
            gx2 = __bfloat162float(gp[2 * HID]);
            gx3 = __bfloat162float(gp[3 * HID]);
        }

        // stage h_{t-1}: poll packed {tag,val} until tag >= tbase+t, drop val in LDS
        if (t == 0) {
            if (tid < 192) { hl[tid] = 0.f; hl[tid + 192] = 0.f; }
        } else if (tid < 192) {
            const unsigned long long* src = hx + ((t + 1) & 1) * HID;
            const unsigned tgt = tbase + (unsigned)t;
            unsigned long long q0, q1;
            long guard = 0;
            do {
                q0 = __hip_atomic_load(src + tid,       __ATOMIC_RELAXED, __HIP_MEMORY_SCOPE_AGENT);
                q1 = __hip_atomic_load(src + tid + 192, __ATOMIC_RELAXED, __HIP_MEMORY_SCOPE_AGENT);
                if ((unsigned)(q0 >> 32) >= tgt && (unsigned)(q1 >> 32) >= tgt) break;
                __builtin_amdgcn_s_sleep(0);
            } while (++guard < (1L << 22));   // hang -> wrong answer, not deadlock
            hl[tid]       = __uint_as_float((unsigned)(q0 & 0xffffffffull));
            hl[tid + 192] = __uint_as_float((unsigned)(q1 & 0xffffffffull));
        }
        __syncthreads();

        // 4 gate dots over this thread's 24 taps (weights in regs, h from LDS)
        float a0 = 0.f, a1 = 0.f, a2 = 0.f, a3 = 0.f;
        #pragma unroll
        for (int j6 = 0; j6 < 6; j6++) {
            const float4 h4 = *(const float4*)(hl + ss * 4 + 64 * j6);
            const float hh[4] = {h4.x, h4.y, h4.z, h4.w};
            #pragma unroll
            for (int e = 0; e < 4; e++) {
                const int j = 4 * j6 + e;
                a0 += w[0][j] * hh[e];
                a1 += w[1][j] * hh[e];
                a2 += w[2][j] * hh[e];
                a3 += w[3][j] * hh[e];
            }
        }
        // reduce over ss (lane bits 0..3)
        a0 += __shfl_xor(a0, 1, 64); a0 += __shfl_xor(a0, 2, 64);
        a0 += __shfl_xor(a0, 4, 64); a0 += __shfl_xor(a0, 8, 64);
        a1 += __shfl_xor(a1, 1, 64); a1 += __shfl_xor(a1, 2, 64);
        a1 += __shfl_xor(a1, 4, 64); a1 += __shfl_xor(a1, 8, 64);
        a2 += __shfl_xor(a2, 1, 64); a2 += __shfl_xor(a2, 2, 64);
        a2 += __shfl_xor(a2, 4, 64); a2 += __shfl_xor(a2, 8, 64);
        a3 += __shfl_xor(a3, 1, 64); a3 += __shfl_xor(a3, 2, 64);
        a3 += __shfl_xor(a3, 4, 64); a3 += __shfl_xor(a3, 8, 64);

        if (owner) {
            const float ii = sigf(a0 + gx0);
            const float ff = sigf(a1 + gx1);
            const float gg = tanhfast(a2 + gx2);
            const float oo = sigf(a3 + gx3);
            c_state = ff * c_state + ii * gg;
            const float hn = oo * tanhfast(c_state);
            // publish packed {tag, h_t} — single 8B atomic, data IS the flag
            const unsigned long long pk =
                ((unsigned long long)(tbase + (unsigned)t + 1u) << 32) |
                (unsigned long long)__float_as_uint(hn);
            __hip_atomic_store(hx + (t & 1) * HID + ug, pk,
                               __ATOMIC_RELAXED, __HIP_MEMORY_SCOPE_AGENT);
            // plain store for downstream kernels (dispatch-end release covers it)
            out[((size_t)(b * S_LEN + tt)) * (2 * HID) + dir * HID + ug] = hn;
        }

        __syncthreads();   // protects hl: no wave starts next staging while others read
    }
}

// ---------------- windowed attention ----------------
// score_j = (h_i*w3 + w2) . h_j   (s1[i] and attn_b are constant over j -> cancel in softmax)
__global__ __launch_bounds__(256) void attn_win(
    const float* __restrict__ hcat,   // [16][1024][768], h in cols 0..383
    const float* __restrict__ attnW,  // [1152] = w1|w2|w3
    float* __restrict__ ocat,         // same buffer, writes cols 384..767
    const int* __restrict__ wsz_p)
{
    __shared__ float q[HID];
    __shared__ float sc[96];
    __shared__ float p[96];
    const int blk = blockIdx.x;
    const int b = blk >> 10, i = blk & 1023;
    const int W = *wsz_p;
    const int jlo = max(i - W, 0), jhi = min(i + W, S_LEN - 1);
    const int nj = jhi - jlo + 1;
    const int tid = threadIdx.x;
    const float* hrow = hcat + (size_t)b * S_LEN * 768;

    if (tid < 96) {
        const float4 hv = *(const float4*)(hrow + (size_t)i * 768 + tid * 4);
        const float4 w3 = *(const float4*)(attnW + 768 + tid * 4);
        const float4 w2 = *(const float4*)(attnW + 384 + tid * 4);
        float4 r;
        r.x = hv.x*w3.x + w2.x; r.y = hv.y*w3.y + w2.y;
        r.z = hv.z*w3.z + w2.z; r.w = hv.w*w3.w + w2.w;
        *(float4*)(q + tid * 4) = r;
    }
    __syncthreads();

    const int wv = tid >> 6, lane = tid & 63;
    for (int jj = wv; jj < nj; jj += 4) {
        const float* hj = hrow + (size_t)(jlo + jj) * 768;
        float s = 0.f;
        #pragma unroll
        for (int c = 0; c < 6; c++) { const int d = lane + 64*c; s += q[d] * hj[d]; }
        #pragma unroll
        for (int st = 1; st < 64; st <<= 1) s += __shfl_xor(s, st, 64);
        if (lane == 0) sc[jj] = s;
    }
    __syncthreads();

    if (tid < 64) {
        float v1 = (tid < nj) ? sc[tid] : -3e38f;
        float v2 = (64 + tid < nj) ? sc[64 + tid] : -3e38f;
        float m = fmaxf(v1, v2);
        #pragma unroll
        for (int st = 1; st < 64; st <<= 1) m = fmaxf(m, __shfl_xor(m, st, 64));
        float e1 = (tid < nj) ? __expf(v1 - m) : 0.f;
        float e2 = (64 + tid < nj) ? __expf(v2 - m) : 0.f;
        float sum = e1 + e2;
        #pragma unroll
        for (int st = 1; st < 64; st <<= 1) sum += __shfl_xor(sum, st, 64);
        const float inv = 1.f / sum;
        if (tid < nj) p[tid] = e1 * inv;
        if (64 + tid < nj) p[64 + tid] = e2 * inv;
    }
    __syncthreads();

    if (tid < 192) {
        const int d = tid * 2;
        float s0 = 0.f, s1 = 0.f;
        for (int jj = 0; jj < nj; jj++) {
            const float* hj = hrow + (size_t)(jlo + jj) * 768 + d;
            const float pj = p[jj];
            s0 += pj * hj[0]; s1 += pj * hj[1];
        }
        float* o = ocat + (size_t)b * S_LEN * 768 + (size_t)i * 768 + 384 + d;
        o[0] = s0; o[1] = s1;
    }
}

// ---------------- final 96 -> 1 dot ----------------
__global__ __launch_bounds__(256) void final_dot(
    const float* __restrict__ y2, const float* __restrict__ W3,
    const float* __restrict__ b3, float* __restrict__ outp)
{
    __shared__ float w[96];
    const int tid = threadIdx.x;
    if (tid < 96) w[tid] = W3[tid];
    __syncthreads();
    const int r = blockIdx.x * 256 + tid;
    const float* row = y2 + (size_t)r * 96;
    float s = 0.f;
    #pragma unroll
    for (int c = 0; c < 24; c++) {
        const float4 v = ((const float4*)row)[c];
        s += v.x*w[c*4] + v.y*w[c*4+1] + v.z*w[c*4+2] + v.w*w[c*4+3];
    }
    outp[r] = s + b3[0];
}

// ---------------- launcher ----------------
extern "C" void kernel_launch(void* const* d_in, const int* in_sizes, int n_in,
                              void* d_out, int out_size, void* d_ws, size_t ws_size,
                              hipStream_t stream)
{
    const float* x        = (const float*)d_in[0];
    const float* l1_Wih_f = (const float*)d_in[1];
    const float* l1_Whh_f = (const float*)d_in[2];
    const float* l1_b_f   = (const float*)d_in[3];
    const float* l1_Wih_b = (const float*)d_in[4];
    const float* l1_Whh_b = (const float*)d_in[5];
    const float* l1_b_b   = (const float*)d_in[6];
    const float* l2_Wih_f = (const float*)d_in[7];
    const float* l2_Whh_f = (const float*)d_in[8];
    const float* l2_b_f   = (const float*)d_in[9];
    const float* l2_Wih_b = (const float*)d_in[10];
    const float* l2_Whh_b = (const float*)d_in[11];
    const float* l2_b_b   = (const float*)d_in[12];
    const float* fc1_W    = (const float*)d_in[13];
    const float* fc1_b    = (const float*)d_in[14];
    const float* attn_W   = (const float*)d_in[15];
    /* d_in[16] attn_b: cancels in softmax */
    const float* w1       = (const float*)d_in[17];
    const float* b1       = (const float*)d_in[18];
    const float* w2       = (const float*)d_in[19];
    const float* b2       = (const float*)d_in[20];
    const float* w3       = (const float*)d_in[21];
    const float* b3       = (const float*)d_in[22];
    const int*   wsz      = (const int*)d_in[23];

    // workspace layout (bytes), peak ~201.5 MiB
    char* wsb = (char*)d_ws;
    __hip_bfloat16*     gF  = (__hip_bfloat16*)(wsb);             // 16384*1536 bf16 = 50,331,648 B
    __hip_bfloat16*     gB  = (__hip_bfloat16*)(wsb +  50331648); // 50,331,648 B
    float*              seq = (float*)(wsb + 100663296);          // 16384*768 f32 = 50,331,648 B
    float*              hct = (float*)(wsb + 150994944);          // 16384*768 f32 = 50,331,648 B
    unsigned long long* hx  = (unsigned long long*)(wsb + 201326592); // 24,576 u64 = 196,608 B
    float*              h2  = (float*)(wsb);                      // 16384*384 f32, aliases gF (dead)
    float*              y1  = (float*)(wsb +  50331648);          // 16384*256 f32, aliases gB (dead)
    float*              y2  = (float*)(wsb +  50331648 + 16777216); // 16384*96 f32

    const int M = BATCH * S_LEN;   // 16384
    dim3 tb(256);

    // ---- layer 1 ----
    zero_kernel<<<dim3(96), tb, 0, stream>>>(hx);
    gemm_nt<0, __hip_bfloat16><<<dim3(M/128, 24), tb, 0, stream>>>(x, DIN, l1_Wih_f, l1_b_f, gF, 1536, M, 1536, DIN);
    gemm_nt<0, __hip_bfloat16><<<dim3(M/128, 24), tb, 0, stream>>>(x, DIN, l1_Wih_b, l1_b_b, gB, 1536, M, 1536, DIN);
    lstm_scan<<<dim3(768), tb, 0, stream>>>(gF, gB, l1_Whh_f, l1_Whh_b, seq, hx, 0);

    // ---- fc1 + windowed attention -> h_cat ----
    gemm_nt<0, float><<<dim3(M/128, 6), tb, 0, stream>>>(seq, 768, fc1_W, fc1_b, hct, 768, M, 384, 768);
    attn_win<<<dim3(M), tb, 0, stream>>>(hct, attn_W, hct, wsz);

    // ---- layer 2 ----  (no re-zero needed: epoch-tagged monotone tags)
    gemm_nt<0, __hip_bfloat16><<<dim3(M/128, 24), tb, 0, stream>>>(hct, 768, l2_Wih_f, l2_b_f, gF, 1536, M, 1536, 768);
    gemm_nt<0, __hip_bfloat16><<<dim3(M/128, 24), tb, 0, stream>>>(hct, 768, l2_Wih_b, l2_b_b, gB, 1536, M, 1536, 768);
    lstm_scan<<<dim3(768), tb, 0, stream>>>(gF, gB, l2_Whh_f, l2_Whh_b, seq, hx, 1);

    // ---- head: fc1 again, then MLP ----
    gemm_nt<0, float><<<dim3(M/128, 6), tb, 0, stream>>>(seq, 768, fc1_W, fc1_b, h2, 384, M, 384, 768);
    gemm_nt<1, float><<<dim3(M/128, 4), tb, 0, stream>>>(h2, 384, w1, b1, y1, 256, M, 256, 384);
    gemm_nt<1, float><<<dim3(M/128, 2), tb, 0, stream>>>(y1, 256, w2, b2, y2, 96, M, 96, 256);
    final_dot<<<dim3(M/256), tb, 0, stream>>>(y2, w3, b3, (float*)d_out);
}

// Round 6
// 7107.581 us; speedup vs baseline: 4.8251x; 1.1251x over previous
//
#include <hip/hip_runtime.h>
#include <hip/hip_bf16.h>
#include <type_traits>

#define S_LEN 1024
#define BATCH 16
#define HID   384
#define DIN   768

// ---------------- LSTM scan configuration ----------------
// 32 groups = (dir, batch); GRP members per group; UPB units per member.
#define GRP 8
#define UPB 48
#define NTHR 384

__device__ __forceinline__ float sigf(float x)     { return 1.f/(1.f + __expf(-x)); }
__device__ __forceinline__ float tanhfast(float x) { return 1.f - 2.f/(__expf(2.f*x) + 1.f); }

// ---------------- zero init: packed h-exchange {tag,val} buffer ----------------
// 32 groups x 2 slots x 384 units x 8B = 196,608 B. Must be zeroed every launch
// (harness poisons d_ws with 0xAA -> tags would read as huge -> stale accept).
__global__ void zero_kernel(unsigned long long* hx)
{
    int i = blockIdx.x * blockDim.x + threadIdx.x;
    if (i < 32*2*HID) hx[i] = 0ull;
}

// ---------------- generic fp32 GEMM: C = act(A @ W^T + bias), OT output ----------------
// A [M,K] ldA, W [N,K], C [M,N] ldC.  BM=128 BN=64 BK=16, 256 threads.
template<int RELU, typename OT>
__global__ __launch_bounds__(256) void gemm_nt(
    const float* __restrict__ A, int ldA,
    const float* __restrict__ W,
    const float* __restrict__ bias,
    OT* __restrict__ C, int ldC,
    int M, int N, int K)
{
    __shared__ float As[16][132];
    __shared__ float Ws[16][68];
    const int tid = threadIdx.x;
    const int m0 = blockIdx.x * 128;
    const int n0 = blockIdx.y * 64;
    const int tm = (tid & 15) * 8;
    const int tn = (tid >> 4) * 4;

    float acc[8][4];
    #pragma unroll
    for (int i = 0; i < 8; i++)
        #pragma unroll
        for (int j = 0; j < 4; j++) acc[i][j] = 0.f;

    const int lrow = tid >> 2;          // 0..63
    const int lk   = (tid & 3) * 4;     // 0,4,8,12

    for (int k0 = 0; k0 < K; k0 += 16) {
        #pragma unroll
        for (int p = 0; p < 2; p++) {
            const int r = lrow + p * 64;
            const float4 av = *(const float4*)(A + (size_t)(m0 + r) * ldA + k0 + lk);
            As[lk+0][r] = av.x; As[lk+1][r] = av.y; As[lk+2][r] = av.z; As[lk+3][r] = av.w;
        }
        {
            float4 wv = make_float4(0.f, 0.f, 0.f, 0.f);
            if (n0 + lrow < N) wv = *(const float4*)(W + (size_t)(n0 + lrow) * K + k0 + lk);
            Ws[lk+0][lrow] = wv.x; Ws[lk+1][lrow] = wv.y; Ws[lk+2][lrow] = wv.z; Ws[lk+3][lrow] = wv.w;
        }
        __syncthreads();
        #pragma unroll
        for (int k = 0; k < 16; k++) {
            const float4 a0 = *(const float4*)&As[k][tm];
            const float4 a1 = *(const float4*)&As[k][tm + 4];
            const float4 bv = *(const float4*)&Ws[k][tn];
            const float am[8] = {a0.x, a0.y, a0.z, a0.w, a1.x, a1.y, a1.z, a1.w};
            const float bb[4] = {bv.x, bv.y, bv.z, bv.w};
            #pragma unroll
            for (int i = 0; i < 8; i++)
                #pragma unroll
                for (int j = 0; j < 4; j++) acc[i][j] += am[i] * bb[j];
        }
        __syncthreads();
    }

    #pragma unroll
    for (int i = 0; i < 8; i++) {
        const int m = m0 + tm + i;
        #pragma unroll
        for (int j = 0; j < 4; j++) {
            const int n = n0 + tn + j;
            if (n < N) {
                float v = acc[i][j] + bias[n];
                if (RELU) v = fmaxf(v, 0.f);
                if constexpr (std::is_same_v<OT, __hip_bfloat16>)
                    C[(size_t)m * ldC + n] = __float2bfloat16(v);
                else
                    C[(size_t)m * ldC + n] = v;
            }
        }
    }
}

// ---------------- persistent LSTM scan (one layer, both directions) ----------------
// grid = 256 blocks (1/CU) = 32 groups (dir,batch) x 8 members; 384 threads; 3KB LDS.
// Member m owns units [m*48, m*48+48). Thread (rr=tid>>3, ss=tid&7): unit rr,
// k-taps {ss*4 + 32*j + e}, j<12. LDS h reads: 8 unique float4 addrs/wave spanning
// all 32 banks; same-address lanes broadcast -> conflict-free.
// h exchange: packed 8B {tag(hi32), val(lo32)} agent-scope atomics; data IS the flag
// (no ordering constraints -> no fences, no store-drain requirement).
// Pollers: tid<128, 3 packets each, per-element ready mask + s_sleep backoff
// (cuts IC hot-line congestion). hl double-buffered -> ONE barrier per step.
// 2-slot rotation: publish(step s) -> slot s&1 tag s+1; stage(step s) polls slot
// (s-1)&1 for tags >= s. A slot is overwritten 2 steps after its last reader.
__global__ __launch_bounds__(NTHR) void lstm_scan(
    const __hip_bfloat16* __restrict__ gatesF, const __hip_bfloat16* __restrict__ gatesB,
    const float* __restrict__ WhhF,            const float* __restrict__ WhhB,
    float* __restrict__ out, unsigned long long* hx_all, int epoch)
{
    __shared__ float hl[2][HID];

    const int blk = blockIdx.x;
    const int g   = blk & 31;          // group (members share blk%8 -> likely same XCD; perf hint only)
    const int m   = blk >> 5;          // member 0..7
    const int dir = g >> 4;
    const int b   = g & 15;
    const int u0  = m * UPB;

    const __hip_bfloat16* gates = dir ? gatesB : gatesF;
    const float* Whh = dir ? WhhB : WhhF;
    unsigned long long* hx = hx_all + g * (2 * HID);   // [2 slots][384] packed

    const int tid = threadIdx.x;
    const int rr  = tid >> 3;          // local unit 0..47
    const int ss  = tid & 7;           // k-part 0..7
    const int ug  = u0 + rr;
    const bool owner = (ss == 0);

    // weight slice, taps k = ss*4 + 32*j + e  (compiler may keep in regs or stream L2)
    float w[4][UPB];
    #pragma unroll
    for (int gt = 0; gt < 4; gt++) {
        const float* wp = Whh + ((size_t)gt * HID + ug) * HID + ss * 4;
        #pragma unroll
        for (int j = 0; j < 12; j++) {
            const float4 v = *(const float4*)(wp + 32 * j);
            w[gt][4*j+0] = v.x; w[gt][4*j+1] = v.y;
            w[gt][4*j+2] = v.z; w[gt][4*j+3] = v.w;
        }
    }

    float c_state = 0.f;
    const unsigned tbase = (unsigned)epoch * 2048u;

    for (int t = 0; t < S_LEN; t++) {
        const int tt = dir ? (S_LEN - 1 - t) : t;

        // issue this step's gate-preact loads early (independent of the poll)
        float gx0 = 0.f, gx1 = 0.f, gx2 = 0.f, gx3 = 0.f;
        if (owner) {
            const __hip_bfloat16* gp = gates + ((size_t)(b * S_LEN + tt)) * (4 * HID) + ug;
            gx0 = __bfloat162float(gp[0]);
            gx1 = __bfloat162float(gp[HID]);
            gx2 = __bfloat162float(gp[2 * HID]);
            gx3 = __bfloat162float(gp[3 * HID]);
        }

        // stage h_{t-1} into hl[t&1]: poll packed {tag,val}, per-element ready mask
        if (t == 0) {
            if (tid < 128) {
                hl[0][tid] = 0.f; hl[0][tid + 128] = 0.f; hl[0][tid + 256] = 0.f;
            }
        } else if (tid < 128) {
            const unsigned long long* src = hx + ((t + 1) & 1) * HID;
            float* dst = hl[t & 1];
            const unsigned tgt = tbase + (unsigned)t;
            int pend = 7;
            long guard = 0;
            do {
                if (pend & 1) {
                    const unsigned long long q = __hip_atomic_load(src + tid,
                        __ATOMIC_RELAXED, __HIP_MEMORY_SCOPE_AGENT);
                    if ((unsigned)(q >> 32) >= tgt) {
                        dst[tid] = __uint_as_float((unsigned)q); pend &= ~1;
                    }
                }
                if (pend & 2) {
                    const unsigned long long q = __hip_atomic_load(src + tid + 128,
                        __ATOMIC_RELAXED, __HIP_MEMORY_SCOPE_AGENT);
                    if ((unsigned)(q >> 32) >= tgt) {
                        dst[tid + 128] = __uint_as_float((unsigned)q); pend &= ~2;
                    }
                }
                if (pend & 4) {
                    const unsigned long long q = __hip_atomic_load(src + tid + 256,
                        __ATOMIC_RELAXED, __HIP_MEMORY_SCOPE_AGENT);
                    if ((unsigned)(q >> 32) >= tgt) {
                        dst[tid + 256] = __uint_as_float((unsigned)q); pend &= ~4;
                    }
                }
                if (!pend) break;
                __builtin_amdgcn_s_sleep(1);   // backoff: cut IC hot-line congestion
            } while (++guard < (1L << 22));    // hang -> wrong answer, not deadlock
        }
        __syncthreads();   // the ONLY barrier per step (hl is double-buffered)

        // 4 gate dots over this thread's 48 taps (h from LDS, broadcast-friendly)
        const float* hsl = hl[t & 1];
        float a0 = 0.f, a1 = 0.f, a2 = 0.f, a3 = 0.f;
        #pragma unroll
        for (int j = 0; j < 12; j++) {
            const float4 h4 = *(const float4*)(hsl + ss * 4 + 32 * j);
            const float hh[4] = {h4.x, h4.y, h4.z, h4.w};
            #pragma unroll
            for (int e = 0; e < 4; e++) {
                a0 += w[0][4*j+e] * hh[e];
                a1 += w[1][4*j+e] * hh[e];
                a2 += w[2][4*j+e] * hh[e];
                a3 += w[3][4*j+e] * hh[e];
            }
        }
        // reduce over ss (lane bits 0..2)
        a0 += __shfl_xor(a0, 1, 64); a0 += __shfl_xor(a0, 2, 64); a0 += __shfl_xor(a0, 4, 64);
        a1 += __shfl_xor(a1, 1, 64); a1 += __shfl_xor(a1, 2, 64); a1 += __shfl_xor(a1, 4, 64);
        a2 += __shfl_xor(a2, 1, 64); a2 += __shfl_xor(a2, 2, 64); a2 += __shfl_xor(a2, 4, 64);
        a3 += __shfl_xor(a3, 1, 64); a3 += __shfl_xor(a3, 2, 64); a3 += __shfl_xor(a3, 4, 64);

        if (owner) {
            const float ii = sigf(a0 + gx0);
            const float ff = sigf(a1 + gx1);
            const float gg = tanhfast(a2 + gx2);
            const float oo = sigf(a3 + gx3);
            c_state = ff * c_state + ii * gg;
            const float hn = oo * tanhfast(c_state);
            // publish packed {tag, h_t} — single 8B atomic, data IS the flag
            const unsigned long long pk =
                ((unsigned long long)(tbase + (unsigned)t + 1u) << 32) |
                (unsigned long long)__float_as_uint(hn);
            __hip_atomic_store(hx + (t & 1) * HID + ug, pk,
                               __ATOMIC_RELAXED, __HIP_MEMORY_SCOPE_AGENT);
            // plain store for downstream kernels (dispatch-end release covers it)
            out[((size_t)(b * S_LEN + tt)) * (2 * HID) + dir * HID + ug] = hn;
        }
        // no second barrier: pollers of step t+1 write hl[(t+1)&1], disjoint from hl[t&1]
    }
}

// ---------------- windowed attention ----------------
// score_j = (h_i*w3 + w2) . h_j   (s1[i] and attn_b are constant over j -> cancel in softmax)
__global__ __launch_bounds__(256) void attn_win(
    const float* __restrict__ hcat,   // [16][1024][768], h in cols 0..383
    const float* __restrict__ attnW,  // [1152] = w1|w2|w3
    float* __restrict__ ocat,         // same buffer, writes cols 384..767
    const int* __restrict__ wsz_p)
{
    __shared__ float q[HID];
    __shared__ float sc[96];
    __shared__ float p[96];
    const int blk = blockIdx.x;
    const int b = blk >> 10, i = blk & 1023;
    const int W = *wsz_p;
    const int jlo = max(i - W, 0), jhi = min(i + W, S_LEN - 1);
    const int nj = jhi - jlo + 1;
    const int tid = threadIdx.x;
    const float* hrow = hcat + (size_t)b * S_LEN * 768;

    if (tid < 96) {
        const float4 hv = *(const float4*)(hrow + (size_t)i * 768 + tid * 4);
        const float4 w3 = *(const float4*)(attnW + 768 + tid * 4);
        const float4 w2 = *(const float4*)(attnW + 384 + tid * 4);
        float4 r;
        r.x = hv.x*w3.x + w2.x; r.y = hv.y*w3.y + w2.y;
        r.z = hv.z*w3.z + w2.z; r.w = hv.w*w3.w + w2.w;
        *(float4*)(q + tid * 4) = r;
    }
    __syncthreads();

    const int wv = tid >> 6, lane = tid & 63;
    for (int jj = wv; jj < nj; jj += 4) {
        const float* hj = hrow + (size_t)(jlo + jj) * 768;
        float s = 0.f;
        #pragma unroll
        for (int c = 0; c < 6; c++) { const int d = lane + 64*c; s += q[d] * hj[d]; }
        #pragma unroll
        for (int st = 1; st < 64; st <<= 1) s += __shfl_xor(s, st, 64);
        if (lane == 0) sc[jj] = s;
    }
    __syncthreads();

    if (tid < 64) {
        float v1 = (tid < nj) ? sc[tid] : -3e38f;
        float v2 = (64 + tid < nj) ? sc[64 + tid] : -3e38f;
        float m = fmaxf(v1, v2);
        #pragma unroll
        for (int st = 1; st < 64; st <<= 1) m = fmaxf(m, __shfl_xor(m, st, 64));
        float e1 = (tid < nj) ? __expf(v1 - m) : 0.f;
        float e2 = (64 + tid < nj) ? __expf(v2 - m) : 0.f;
        float sum = e1 + e2;
        #pragma unroll
        for (int st = 1; st < 64; st <<= 1) sum += __shfl_xor(sum, st, 64);
        const float inv = 1.f / sum;
        if (tid < nj) p[tid] = e1 * inv;
        if (64 + tid < nj) p[64 + tid] = e2 * inv;
    }
    __syncthreads();

    if (tid < 192) {
        const int d = tid * 2;
        float s0 = 0.f, s1 = 0.f;
        for (int jj = 0; jj < nj; jj++) {
            const float* hj = hrow + (size_t)(jlo + jj) * 768 + d;
            const float pj = p[jj];
            s0 += pj * hj[0]; s1 += pj * hj[1];
        }
        float* o = ocat + (size_t)b * S_LEN * 768 + (size_t)i * 768 + 384 + d;
        o[0] = s0; o[1] = s1;
    }
}

// ---------------- final 96 -> 1 dot ----------------
__global__ __launch_bounds__(256) void final_dot(
    const float* __restrict__ y2, const float* __restrict__ W3,
    const float* __restrict__ b3, float* __restrict__ outp)
{
    __shared__ float w[96];
    const int tid = threadIdx.x;
    if (tid < 96) w[tid] = W3[tid];
    __syncthreads();
    const int r = blockIdx.x * 256 + tid;
    const float* row = y2 + (size_t)r * 96;
    float s = 0.f;
    #pragma unroll
    for (int c = 0; c < 24; c++) {
        const float4 v = ((const float4*)row)[c];
        s += v.x*w[c*4] + v.y*w[c*4+1] + v.z*w[c*4+2] + v.w*w[c*4+3];
    }
    outp[r] = s + b3[0];
}

// ---------------- launcher ----------------
extern "C" void kernel_launch(void* const* d_in, const int* in_sizes, int n_in,
                              void* d_out, int out_size, void* d_ws, size_t ws_size,
                              hipStream_t stream)
{
    const float* x        = (const float*)d_in[0];
    const float* l1_Wih_f = (const float*)d_in[1];
    const float* l1_Whh_f = (const float*)d_in[2];
    const float* l1_b_f   = (const float*)d_in[3];
    const float* l1_Wih_b = (const float*)d_in[4];
    const float* l1_Whh_b = (const float*)d_in[5];
    const float* l1_b_b   = (const float*)d_in[6];
    const float* l2_Wih_f = (const float*)d_in[7];
    const float* l2_Whh_f = (const float*)d_in[8];
    const float* l2_b_f   = (const float*)d_in[9];
    const float* l2_Wih_b = (const float*)d_in[10];
    const float* l2_Whh_b = (const float*)d_in[11];
    const float* l2_b_b   = (const float*)d_in[12];
    const float* fc1_W    = (const float*)d_in[13];
    const float* fc1_b    = (const float*)d_in[14];
    const float* attn_W   = (const float*)d_in[15];
    /* d_in[16] attn_b: cancels in softmax */
    const float* w1       = (const float*)d_in[17];
    const float* b1       = (const float*)d_in[18];
    const float* w2       = (const float*)d_in[19];
    const float* b2       = (const float*)d_in[20];
    const float* w3       = (const float*)d_in[21];
    const float* b3       = (const float*)d_in[22];
    const int*   wsz      = (const int*)d_in[23];

    // workspace layout (bytes), peak ~201.5 MiB
    char* wsb = (char*)d_ws;
    __hip_bfloat16*     gF  = (__hip_bfloat16*)(wsb);             // 16384*1536 bf16 = 50,331,648 B
    __hip_bfloat16*     gB  = (__hip_bfloat16*)(wsb +  50331648); // 50,331,648 B
    float*              seq = (float*)(wsb + 100663296);          // 16384*768 f32 = 50,331,648 B
    float*              hct = (float*)(wsb + 150994944);          // 16384*768 f32 = 50,331,648 B
    unsigned long long* hx  = (unsigned long long*)(wsb + 201326592); // 24,576 u64 = 196,608 B
    float*              h2  = (float*)(wsb);                      // 16384*384 f32, aliases gF (dead)
    float*              y1  = (float*)(wsb +  50331648);          // 16384*256 f32, aliases gB (dead)
    float*              y2  = (float*)(wsb +  50331648 + 16777216); // 16384*96 f32

    const int M = BATCH * S_LEN;   // 16384
    dim3 tb(256);

    // ---- layer 1 ----
    zero_kernel<<<dim3(96), tb, 0, stream>>>(hx);
    gemm_nt<0, __hip_bfloat16><<<dim3(M/128, 24), tb, 0, stream>>>(x, DIN, l1_Wih_f, l1_b_f, gF, 1536, M, 1536, DIN);
    gemm_nt<0, __hip_bfloat16><<<dim3(M/128, 24), tb, 0, stream>>>(x, DIN, l1_Wih_b, l1_b_b, gB, 1536, M, 1536, DIN);
    lstm_scan<<<dim3(256), dim3(NTHR), 0, stream>>>(gF, gB, l1_Whh_f, l1_Whh_b, seq, hx, 0);

    // ---- fc1 + windowed attention -> h_cat ----
    gemm_nt<0, float><<<dim3(M/128, 6), tb, 0, stream>>>(seq, 768, fc1_W, fc1_b, hct, 768, M, 384, 768);
    attn_win<<<dim3(M), tb, 0, stream>>>(hct, attn_W, hct, wsz);

    // ---- layer 2 ----  (no re-zero needed: epoch-tagged monotone tags)
    gemm_nt<0, __hip_bfloat16><<<dim3(M/128, 24), tb, 0, stream>>>(hct, 768, l2_Wih_f, l2_b_f, gF, 1536, M, 1536, 768);
    gemm_nt<0, __hip_bfloat16><<<dim3(M/128, 24), tb, 0, stream>>>(hct, 768, l2_Wih_b, l2_b_b, gB, 1536, M, 1536, 768);
    lstm_scan<<<dim3(256), dim3(NTHR), 0, stream>>>(gF, gB, l2_Whh_f, l2_Whh_b, seq, hx, 1);

    // ---- head: fc1 again, then MLP ----
    gemm_nt<0, float><<<dim3(M/128, 6), tb, 0, stream>>>(seq, 768, fc1_W, fc1_b, h2, 384, M, 384, 768);
    gemm_nt<1, float><<<dim3(M/128, 4), tb, 0, stream>>>(h2, 384, w1, b1, y1, 256, M, 256, 384);
    gemm_nt<1, float><<<dim3(M/128, 2), tb, 0, stream>>>(y1, 256, w2, b2, y2, 96, M, 96, 256);
    final_dot<<<dim3(M/256), tb, 0, stream>>>(y2, w3, b3, (float*)d_out);
}